// Round 4
// baseline (457.853 us; speedup 1.0000x reference)
//
#include <hip/hip_runtime.h>

#define Bv 64
#define Tv 2048
#define Hv 1024
#define Uv 128
#define Mv 512

typedef __bf16 bf16x8 __attribute__((ext_vector_type(8)));
typedef float f32x4 __attribute__((ext_vector_type(4)));

union U4BF { uint4 u; bf16x8 b; };

#define MFMA(a, b, c) __builtin_amdgcn_mfma_f32_16x16x32_bf16((a), (b), (c), 0, 0, 0)

// async global->LDS, 16B per lane, dest = wave-uniform base + lane*16
#define GLOAD_LDS16(g, l) __builtin_amdgcn_global_load_lds( \
    (const __attribute__((address_space(1))) unsigned int*)(g), \
    (__attribute__((address_space(3))) unsigned int*)(l), 16, 0, 0)

__device__ __forceinline__ unsigned short f2bf(float f) {
  __bf16 h = (__bf16)f;
  return __builtin_bit_cast(unsigned short, h);
}
__device__ __forceinline__ unsigned int pack2(unsigned short lo, unsigned short hi) {
  return (unsigned int)lo | ((unsigned int)hi << 16);
}

// ---------------- k1: pq[b,u] = query@Wq + bq  (bx<512)  |  W2/bias2 fold (bx==512) ----------------
__global__ __launch_bounds__(128) void k1_kernel(const float* __restrict__ query,
                                                 const float* __restrict__ Wq,
                                                 const float* __restrict__ bq,
                                                 const float* __restrict__ Wl,
                                                 const float* __restrict__ bl,
                                                 const float* __restrict__ conv_w,
                                                 const float* __restrict__ conv_b,
                                                 float* __restrict__ pq,
                                                 float* __restrict__ W2,
                                                 float* __restrict__ bias2) {
  const int bx = blockIdx.x;
  const int u = threadIdx.x;
  if (bx < 512) {
    const int b = bx >> 3, c = bx & 7;
    float acc = (c == 0) ? bq[u] : 0.0f;
    const float* q  = query + b * Hv + c * 128;
    const float* wq = Wq + (size_t)c * 128 * Uv;
    #pragma unroll 8
    for (int h = 0; h < 128; ++h) acc = fmaf(q[h], wq[h * Uv + u], acc);
    unsafeAtomicAdd(&pq[b * Uv + u], acc);
  } else {
    float wl[32];
    #pragma unroll
    for (int f = 0; f < 32; ++f) wl[f] = Wl[f * Uv + u];
    for (int k = 0; k < 31; ++k) {
      float acc = 0.0f;
      #pragma unroll
      for (int f = 0; f < 32; ++f) acc = fmaf(conv_w[f * 31 + k], wl[f], acc);
      W2[k * Uv + u] = acc;
    }
    float acc = bl[u];
    #pragma unroll
    for (int f = 0; f < 32; ++f) acc = fmaf(conv_b[f], wl[f], acc);
    bias2[u] = acc;
  }
}

// ---------------- k2: qe[b,n] = (pq[b]+bias2+bm)@We + be ;  w3tmp[k,n] = W2@We (rows 64..95) ----------------
__global__ __launch_bounds__(256) void k2_kernel(const float* __restrict__ pq,
                                                 const float* __restrict__ bias2,
                                                 const float* __restrict__ bm,
                                                 const float* __restrict__ be,
                                                 const float* __restrict__ We,
                                                 const float* __restrict__ W2,
                                                 float* __restrict__ qe,
                                                 float* __restrict__ w3tmp) {
  const int gtid = blockIdx.x * 256 + threadIdx.x;
  const int r = gtid >> 7, n = gtid & 127;
  if (r < 64) {
    float acc = be[n];
    for (int u = 0; u < Uv; ++u)
      acc = fmaf(pq[r * Uv + u] + bias2[u] + bm[u], We[u * Uv + n], acc);
    qe[r * Uv + n] = acc;
  } else {
    const int w = r - 64;
    float acc = 0.0f;
    if (w < 31) {
      for (int u = 0; u < Uv; ++u) acc = fmaf(W2[w * Uv + u], We[u * Uv + n], acc);
    }
    w3tmp[w * Uv + n] = acc;
  }
}

// ---------------- k3: pack Wm / We / w3tmp into bf16 MFMA B-fragment layout ----------------
__global__ __launch_bounds__(256) void k3_kernel(const float* __restrict__ Wm,
                                                 const float* __restrict__ We,
                                                 const float* __restrict__ w3tmp,
                                                 unsigned short* __restrict__ WmF,
                                                 unsigned short* __restrict__ WeF,
                                                 unsigned short* __restrict__ W3F) {
  const int gtid = blockIdx.x * 256 + threadIdx.x;
  const int fid = gtid >> 6, lane = gtid & 63;
  const int quad = lane >> 4, l4 = lane & 15;
  float v[8];
  unsigned short* dst;
  if (fid < 128) {                    // Wm: 16 kc x 8 uj
    const int kc = fid >> 3, uj = fid & 7;
    #pragma unroll
    for (int j = 0; j < 8; ++j) v[j] = Wm[(size_t)(kc * 32 + quad * 8 + j) * Uv + uj * 16 + l4];
    dst = WmF + (size_t)fid * 512 + lane * 8;
  } else if (fid < 160) {             // We: 4 kc x 8 nj
    const int f2 = fid - 128;
    const int kc = f2 >> 3, nj = f2 & 7;
    #pragma unroll
    for (int j = 0; j < 8; ++j) v[j] = We[(size_t)(kc * 32 + quad * 8 + j) * Uv + nj * 16 + l4];
    dst = WeF + (size_t)f2 * 512 + lane * 8;
  } else {                            // W3: 1 kc x 8 nj
    const int nj = fid - 160;
    #pragma unroll
    for (int j = 0; j < 8; ++j) v[j] = w3tmp[(quad * 8 + j) * Uv + nj * 16 + l4];
    dst = W3F + (size_t)nj * 512 + lane * 8;
  }
  uint4 o;
  o.x = pack2(f2bf(v[0]), f2bf(v[1]));
  o.y = pack2(f2bf(v[2]), f2bf(v[3]));
  o.z = pack2(f2bf(v[4]), f2bf(v[5]));
  o.w = pack2(f2bf(v[6]), f2bf(v[7]));
  *(uint4*)dst = o;
}

// ---------------- main fused kernel ----------------
// Phase 1: double-buffered K=64 staging (two round-1-style K=32 sub-buffers
// per outer chunk) via global_load_lds, XOR-swizzled both-sides. 8 outer
// chunks -> 8 __syncthreads drains (was 16), each preceded by a full
// 16-MFMA compute phase so the prefetch issued at loop top has ~500cy to
// land. Plain HIP only: no inline asm, no raw s_barrier. Staging region
// aliases the sS pm-tile (disjoint live ranges; the loop's final
// __syncthreads separates last sA read from first sS write).
__global__ __launch_bounds__(256) void main_kernel(
    const float* __restrict__ memory, const unsigned short* __restrict__ WmF,
    const unsigned short* __restrict__ WeF, const unsigned short* __restrict__ W3F,
    const float* __restrict__ qe, const float* __restrict__ state,
    const float* __restrict__ prev_cum, const float* __restrict__ bm,
    const float* __restrict__ va,
    float* __restrict__ P0, float* __restrict__ P1, float* __restrict__ Ssg) {
  const int tid = threadIdx.x;
  const int lane = tid & 63, wid = tid >> 6;
  const int l4 = lane & 15, quad = lane >> 4;
  const int wt = wid >> 1, wu = wid & 1;
  const int b = blockIdx.y, t0 = blockIdx.x * 64;

  __shared__ float sState[124];
  __shared__ float sPc[64];
  __shared__ float sBm[128];
  __shared__ float sVa[128];
  __shared__ float sSg[64];
  __shared__ float blkP0[128], blkP1[128];
  __shared__ float blkSsg;
  // sA: 2 bufs x 2 subs x 2048 floats (32768 B), aliased with sS[64*144] bf16 (18432 B)
  __shared__ __align__(16) char smem[32768];
  float* sAf = (float*)smem;
  unsigned short* sS = (unsigned short*)smem;

  // ---- staging source addresses (per lane, chunk-invariant). Within a K=32
  // sub-buffer, physical 16B slot p holds logical (row = p>>3, c4 = (p&7) ^
  // (row&7)) -> inverse-swizzled source (round-1 verified mapping).
  const int p0 = tid, p1 = tid + 256;
  const int sr0 = p0 >> 3, sc0 = (p0 & 7) ^ (sr0 & 7);
  const int sr1 = p1 >> 3, sc1 = (p1 & 7) ^ (sr1 & 7);
  const float* g0 = memory + ((size_t)b * Tv + t0 + sr0) * Mv + sc0 * 4;
  const float* g1 = memory + ((size_t)b * Tv + t0 + sr1) * Mv + sc1 * 4;

  // ---- prologue: stage outer chunk 0 (subs 0,1) into buffer 0
  {
    float* d = sAf + wid * 256;
    GLOAD_LDS16(g0, d);           GLOAD_LDS16(g1, d + 1024);
    GLOAD_LDS16(g0 + 32, d + 2048); GLOAD_LDS16(g1 + 32, d + 3072);
  }

  // ---- init small LDS
  for (int i = tid; i < 124; i += 256) {
    int t = t0 - 30 + i;
    sState[i] = (t >= 0 && t < Tv) ? state[b * Tv + t] : 0.0f;
  }
  if (tid < 64) sPc[tid] = prev_cum[b * Tv + t0 + tid];
  for (int i = tid; i < 128; i += 256) {
    sBm[i] = bm[i]; sVa[i] = va[i]; blkP0[i] = 0.0f; blkP1[i] = 0.0f;
  }
  if (tid == 0) blkSsg = 0.0f;

  // ---- swizzled LDS read offsets (float4 units), chunk-invariant
  const int r0 = wt * 32 + l4;
  const int q2 = quad * 2, rx = r0 & 7;
  const int s00 = r0 * 8 + (q2 ^ rx);
  const int s01 = r0 * 8 + ((q2 + 1) ^ rx);

  f32x4 acc[2][4];
  #pragma unroll
  for (int ti = 0; ti < 2; ++ti)
    #pragma unroll
    for (int uj = 0; uj < 4; ++uj) acc[ti][uj] = (f32x4){0.f, 0.f, 0.f, 0.f};

  const unsigned short* bBase = WmF + (size_t)(wu * 4) * 512 + lane * 8;

  auto chunk = [&](const uint4& B0, const uint4& B1, const uint4& B2, const uint4& B3,
                   int base) {
    const float4* sf = (const float4*)(sAf + base);
    float4 a0 = sf[s00];
    float4 a1 = sf[s01];
    float4 a2 = sf[s00 + 128];
    float4 a3 = sf[s01 + 128];
    bf16x8 af0, af1;
    af0[0] = (__bf16)a0.x; af0[1] = (__bf16)a0.y; af0[2] = (__bf16)a0.z; af0[3] = (__bf16)a0.w;
    af0[4] = (__bf16)a1.x; af0[5] = (__bf16)a1.y; af0[6] = (__bf16)a1.z; af0[7] = (__bf16)a1.w;
    af1[0] = (__bf16)a2.x; af1[1] = (__bf16)a2.y; af1[2] = (__bf16)a2.z; af1[3] = (__bf16)a2.w;
    af1[4] = (__bf16)a3.x; af1[5] = (__bf16)a3.y; af1[6] = (__bf16)a3.z; af1[7] = (__bf16)a3.w;
    U4BF u0, u1, u2, u3;
    u0.u = B0; u1.u = B1; u2.u = B2; u3.u = B3;
    acc[0][0] = MFMA(af0, u0.b, acc[0][0]);
    acc[1][0] = MFMA(af1, u0.b, acc[1][0]);
    acc[0][1] = MFMA(af0, u1.b, acc[0][1]);
    acc[1][1] = MFMA(af1, u1.b, acc[1][1]);
    acc[0][2] = MFMA(af0, u2.b, acc[0][2]);
    acc[1][2] = MFMA(af1, u2.b, acc[1][2]);
    acc[0][3] = MFMA(af0, u3.b, acc[0][3]);
    acc[1][3] = MFMA(af1, u3.b, acc[1][3]);
  };

  __syncthreads();  // buffer 0 staged + init LDS visible

  // ---- phase 1: pm GEMM, 8 outer chunks of K=64 (2 x K=32 sub-chunks)
  for (int oc = 0; oc < 8; ++oc) {
    const int rb = (oc & 1) * 4096;  // read buffer base (floats)
    if (oc < 7) {
      const int wb = ((oc + 1) & 1) * 4096;
      float* d = sAf + wb + wid * 256;
      const float* ga = g0 + (oc + 1) * 64;
      const float* gb = g1 + (oc + 1) * 64;
      GLOAD_LDS16(ga, d);           GLOAD_LDS16(gb, d + 1024);
      GLOAD_LDS16(ga + 32, d + 2048); GLOAD_LDS16(gb + 32, d + 3072);
    }
    // B fragments for kc = 2*oc and 2*oc+1 (L2-resident)
    const unsigned short* pB0 = bBase + (size_t)(2 * oc) * 4096;
    const unsigned short* pB1 = pB0 + 4096;
    uint4 b00 = *(const uint4*)pB0;          uint4 b01 = *(const uint4*)(pB0 + 512);
    uint4 b02 = *(const uint4*)(pB0 + 1024); uint4 b03 = *(const uint4*)(pB0 + 1536);
    uint4 b10 = *(const uint4*)pB1;          uint4 b11 = *(const uint4*)(pB1 + 512);
    uint4 b12 = *(const uint4*)(pB1 + 1024); uint4 b13 = *(const uint4*)(pB1 + 1536);
    chunk(b00, b01, b02, b03, rb);
    chunk(b10, b11, b12, b13, rb + 2048);
    __syncthreads();
  }

  // ---- write pm (bf16) to LDS (aliases staging region; barrier above protects)
  #pragma unroll
  for (int ti = 0; ti < 2; ++ti) {
    const int rowb = wt * 32 + ti * 16 + quad * 4;
    #pragma unroll
    for (int uj = 0; uj < 4; ++uj) {
      const int col = wu * 64 + uj * 16 + l4;
      #pragma unroll
      for (int r = 0; r < 4; ++r) sS[(rowb + r) * 144 + col] = f2bf(acc[ti][uj][r]);
    }
  }
  __syncthreads();

  // ---- phase 2: e2 = pm@We + S2@W3 + qe[b]
  const int w = wid;
  f32x4 e[8];
  #pragma unroll
  for (int nj = 0; nj < 8; ++nj) {
    float qv = qe[b * Uv + nj * 16 + l4];
    e[nj] = (f32x4){qv, qv, qv, qv};
  }
  bf16x8 a2f;
  #pragma unroll
  for (int j = 0; j < 8; ++j) {
    int k = quad * 8 + j;
    float v = (k < 31) ? sState[(w * 16 + l4) + 2 * k] : 0.0f;
    a2f[j] = (__bf16)v;
  }
  #pragma unroll
  for (int nj = 0; nj < 8; ++nj) {
    U4BF bb; bb.u = *(const uint4*)(W3F + (size_t)nj * 512 + lane * 8);
    e[nj] = MFMA(a2f, bb.b, e[nj]);
  }
  #pragma unroll
  for (int ks = 0; ks < 4; ++ks) {
    U4BF au;
    au.u = *(const uint4*)&sS[(w * 16 + l4) * 144 + ks * 32 + quad * 8];
    #pragma unroll
    for (int nj = 0; nj < 8; ++nj) {
      U4BF bb; bb.u = *(const uint4*)(WeF + (size_t)(ks * 8 + nj) * 512 + lane * 8);
      e[nj] = MFMA(au.b, bb.b, e[nj]);
    }
  }
  float p[4] = {0.f, 0.f, 0.f, 0.f};
  #pragma unroll
  for (int nj = 0; nj < 8; ++nj) {
    float vav = sVa[nj * 16 + l4];
    #pragma unroll
    for (int r = 0; r < 4; ++r) p[r] = fmaf(vav, tanhf(e[nj][r]), p[r]);
  }
  #pragma unroll
  for (int off = 1; off <= 8; off <<= 1) {
    #pragma unroll
    for (int r = 0; r < 4; ++r) p[r] += __shfl_xor(p[r], off, 64);
  }
  float sgv4[4], sgsum = 0.f;
  #pragma unroll
  for (int r = 0; r < 4; ++r) {
    sgv4[r] = 1.0f / (1.0f + expf(-p[r]));
    sgsum += sgv4[r];
  }
  if (l4 == 0) {
    #pragma unroll
    for (int r = 0; r < 4; ++r) sSg[w * 16 + quad * 4 + r] = sgv4[r];
    atomicAdd(&blkSsg, sgsum);
  }
  __syncthreads();

  // ---- phase 3: P0/P1 accumulation from pm accumulators
  float sgl[8], pcl[8];
  #pragma unroll
  for (int ti = 0; ti < 2; ++ti)
    #pragma unroll
    for (int r = 0; r < 4; ++r) {
      int row = wt * 32 + ti * 16 + quad * 4 + r;
      sgl[ti * 4 + r] = sSg[row];
      pcl[ti * 4 + r] = sPc[row];
    }
  #pragma unroll
  for (int uj = 0; uj < 4; ++uj) {
    const int col = wu * 64 + uj * 16 + l4;
    const float bmv = sBm[col];
    float c0 = 0.f, c1 = 0.f;
    #pragma unroll
    for (int ti = 0; ti < 2; ++ti)
      #pragma unroll
      for (int r = 0; r < 4; ++r) {
        float pmv = acc[ti][uj][r] + bmv;
        c0 = fmaf(pcl[ti * 4 + r], pmv, c0);
        c1 = fmaf(sgl[ti * 4 + r], pmv, c1);
      }
    c0 += __shfl_xor(c0, 16, 64); c0 += __shfl_xor(c0, 32, 64);
    c1 += __shfl_xor(c1, 16, 64); c1 += __shfl_xor(c1, 32, 64);
    if (quad == 0) {
      atomicAdd(&blkP0[col], c0);
      atomicAdd(&blkP1[col], c1);
    }
  }
  __syncthreads();
  if (tid < 128) {
    unsafeAtomicAdd(&P0[b * Uv + tid], blkP0[tid]);
    unsafeAtomicAdd(&P1[b * Uv + tid], blkP1[tid]);
  }
  if (tid == 0) unsafeAtomicAdd(&Ssg[b], blkSsg);
}

// ---------------- finish: context = P0 + P1 / Ssg ----------------
__global__ __launch_bounds__(128) void finish_kernel(const float* __restrict__ P0,
                                                     const float* __restrict__ P1,
                                                     const float* __restrict__ Ssg,
                                                     float* __restrict__ out) {
  const int b = blockIdx.x, u = threadIdx.x;
  out[b * Uv + u] = P0[b * Uv + u] + P1[b * Uv + u] / Ssg[b];
}

extern "C" void kernel_launch(void* const* d_in, const int* in_sizes, int n_in,
                              void* d_out, int out_size, void* d_ws, size_t ws_size,
                              hipStream_t stream) {
  (void)in_sizes; (void)n_in; (void)out_size; (void)ws_size;
  const float* query    = (const float*)d_in[0];
  const float* state    = (const float*)d_in[1];
  const float* prev_cum = (const float*)d_in[2];
  const float* memory   = (const float*)d_in[3];
  const float* Wq       = (const float*)d_in[4];
  const float* bq       = (const float*)d_in[5];
  const float* Wm       = (const float*)d_in[6];
  const float* bm       = (const float*)d_in[7];
  const float* Wl       = (const float*)d_in[8];
  const float* bl       = (const float*)d_in[9];
  const float* We       = (const float*)d_in[10];
  const float* be       = (const float*)d_in[11];
  const float* va       = (const float*)d_in[12];
  const float* conv_w   = (const float*)d_in[13];
  const float* conv_b   = (const float*)d_in[14];

  float* ws = (float*)d_ws;
  float* P0    = ws;                 // 8192
  float* P1    = ws + 8192;          // 8192
  float* Ssg   = ws + 16384;         // 64
  float* pq    = ws + 16448;         // 8192
  float* W2    = ws + 24640;         // 3968
  float* bias2 = ws + 28608;         // 128
  float* qe    = ws + 28736;         // 8192
  float* w3tmp = ws + 36928;         // 4096 (32x128, row 31 zeroed)
  unsigned short* WmF = (unsigned short*)(ws + 41024);  // 65536 bf16
  unsigned short* WeF = (unsigned short*)(ws + 73792);  // 16384 bf16
  unsigned short* W3F = (unsigned short*)(ws + 81984);  // 4096 bf16

  hipMemsetAsync(d_ws, 0, 24640 * sizeof(float), stream);

  k1_kernel<<<513, 128, 0, stream>>>(query, Wq, bq, Wl, bl, conv_w, conv_b, pq, W2, bias2);
  k2_kernel<<<48, 256, 0, stream>>>(pq, bias2, bm, be, We, W2, qe, w3tmp);
  k3_kernel<<<42, 256, 0, stream>>>(Wm, We, w3tmp, WmF, WeF, W3F);
  main_kernel<<<dim3(Tv / 64, Bv), 256, 0, stream>>>(
      memory, WmF, WeF, W3F, qe, state, prev_cum, bm, va, P0, P1, Ssg);
  finish_kernel<<<Bv, 128, 0, stream>>>(P0, P1, Ssg, (float*)d_out);
}

// Round 5
// 450.924 us; speedup vs baseline: 1.0154x; 1.0154x over previous
//
#include <hip/hip_runtime.h>

#define Bv 64
#define Tv 2048
#define Hv 1024
#define Uv 128
#define Mv 512

typedef __bf16 bf16x8 __attribute__((ext_vector_type(8)));
typedef float f32x4 __attribute__((ext_vector_type(4)));

union U4BF { uint4 u; bf16x8 b; };

#define MFMA(a, b, c) __builtin_amdgcn_mfma_f32_16x16x32_bf16((a), (b), (c), 0, 0, 0)

__device__ __forceinline__ unsigned short f2bf(float f) {
  __bf16 h = (__bf16)f;
  return __builtin_bit_cast(unsigned short, h);
}
__device__ __forceinline__ unsigned int pack2(unsigned short lo, unsigned short hi) {
  return (unsigned int)lo | ((unsigned int)hi << 16);
}
// fast tanh/sigmoid via v_exp (saturates correctly at +/-inf)
__device__ __forceinline__ float tanh_fast(float x) {
  float e = __expf(2.0f * x);
  return 1.0f - 2.0f / (e + 1.0f);
}
__device__ __forceinline__ float sigmoid_fast(float x) {
  return 1.0f / (1.0f + __expf(-x));
}

// ---------------- k1: pq[b,u] = query@Wq + bq  (bx<512)  |  W2/bias2 fold (bx==512) ----------------
__global__ __launch_bounds__(128) void k1_kernel(const float* __restrict__ query,
                                                 const float* __restrict__ Wq,
                                                 const float* __restrict__ bq,
                                                 const float* __restrict__ Wl,
                                                 const float* __restrict__ bl,
                                                 const float* __restrict__ conv_w,
                                                 const float* __restrict__ conv_b,
                                                 float* __restrict__ pq,
                                                 float* __restrict__ W2,
                                                 float* __restrict__ bias2) {
  const int bx = blockIdx.x;
  const int u = threadIdx.x;
  if (bx < 512) {
    const int b = bx >> 3, c = bx & 7;
    float acc = (c == 0) ? bq[u] : 0.0f;
    const float* q  = query + b * Hv + c * 128;
    const float* wq = Wq + (size_t)c * 128 * Uv;
    #pragma unroll 8
    for (int h = 0; h < 128; ++h) acc = fmaf(q[h], wq[h * Uv + u], acc);
    unsafeAtomicAdd(&pq[b * Uv + u], acc);
  } else {
    float wl[32];
    #pragma unroll
    for (int f = 0; f < 32; ++f) wl[f] = Wl[f * Uv + u];
    for (int k = 0; k < 31; ++k) {
      float acc = 0.0f;
      #pragma unroll
      for (int f = 0; f < 32; ++f) acc = fmaf(conv_w[f * 31 + k], wl[f], acc);
      W2[k * Uv + u] = acc;
    }
    float acc = bl[u];
    #pragma unroll
    for (int f = 0; f < 32; ++f) acc = fmaf(conv_b[f], wl[f], acc);
    bias2[u] = acc;
  }
}

// ---------------- k2: qe[b,n] = (pq[b]+bias2+bm)@We + be ;  w3tmp[k,n] = W2@We (rows 64..95) ----------------
__global__ __launch_bounds__(256) void k2_kernel(const float* __restrict__ pq,
                                                 const float* __restrict__ bias2,
                                                 const float* __restrict__ bm,
                                                 const float* __restrict__ be,
                                                 const float* __restrict__ We,
                                                 const float* __restrict__ W2,
                                                 float* __restrict__ qe,
                                                 float* __restrict__ w3tmp) {
  const int gtid = blockIdx.x * 256 + threadIdx.x;
  const int r = gtid >> 7, n = gtid & 127;
  if (r < 64) {
    float acc = be[n];
    for (int u = 0; u < Uv; ++u)
      acc = fmaf(pq[r * Uv + u] + bias2[u] + bm[u], We[u * Uv + n], acc);
    qe[r * Uv + n] = acc;
  } else {
    const int w = r - 64;
    float acc = 0.0f;
    if (w < 31) {
      for (int u = 0; u < Uv; ++u) acc = fmaf(W2[w * Uv + u], We[u * Uv + n], acc);
    }
    w3tmp[w * Uv + n] = acc;
  }
}

// ---------------- k3: pack Wm / We / w3tmp into bf16 MFMA B-fragment layout ----------------
__global__ __launch_bounds__(256) void k3_kernel(const float* __restrict__ Wm,
                                                 const float* __restrict__ We,
                                                 const float* __restrict__ w3tmp,
                                                 unsigned short* __restrict__ WmF,
                                                 unsigned short* __restrict__ WeF,
                                                 unsigned short* __restrict__ W3F) {
  const int gtid = blockIdx.x * 256 + threadIdx.x;
  const int fid = gtid >> 6, lane = gtid & 63;
  const int quad = lane >> 4, l4 = lane & 15;
  float v[8];
  unsigned short* dst;
  if (fid < 128) {                    // Wm: 16 kc x 8 uj
    const int kc = fid >> 3, uj = fid & 7;
    #pragma unroll
    for (int j = 0; j < 8; ++j) v[j] = Wm[(size_t)(kc * 32 + quad * 8 + j) * Uv + uj * 16 + l4];
    dst = WmF + (size_t)fid * 512 + lane * 8;
  } else if (fid < 160) {             // We: 4 kc x 8 nj
    const int f2 = fid - 128;
    const int kc = f2 >> 3, nj = f2 & 7;
    #pragma unroll
    for (int j = 0; j < 8; ++j) v[j] = We[(size_t)(kc * 32 + quad * 8 + j) * Uv + nj * 16 + l4];
    dst = WeF + (size_t)f2 * 512 + lane * 8;
  } else {                            // W3: 1 kc x 8 nj
    const int nj = fid - 160;
    #pragma unroll
    for (int j = 0; j < 8; ++j) v[j] = w3tmp[(quad * 8 + j) * Uv + nj * 16 + l4];
    dst = W3F + (size_t)nj * 512 + lane * 8;
  }
  uint4 o;
  o.x = pack2(f2bf(v[0]), f2bf(v[1]));
  o.y = pack2(f2bf(v[2]), f2bf(v[3]));
  o.z = pack2(f2bf(v[4]), f2bf(v[5]));
  o.w = pack2(f2bf(v[6]), f2bf(v[7]));
  *(uint4*)dst = o;
}

// ---------------- main fused kernel ----------------
// Phase 1: register-direct A loads with an explicit 4-deep software pipeline
// (fully unrolled k-loop -> static buffer indices). NO LDS staging, NO
// barriers in phase 1: each wave free-runs with compiler-counted vmcnt waits,
// so latency tolerance is per-wave, not block-convoyed. B-fragments (L2)
// are 1-deep prefetched. Phase 2 uses fast exp-based tanh/sigmoid.
__global__ __launch_bounds__(256) void main_kernel(
    const float* __restrict__ memory, const unsigned short* __restrict__ WmF,
    const unsigned short* __restrict__ WeF, const unsigned short* __restrict__ W3F,
    const float* __restrict__ qe, const float* __restrict__ state,
    const float* __restrict__ prev_cum, const float* __restrict__ bm,
    const float* __restrict__ va,
    float* __restrict__ P0, float* __restrict__ P1, float* __restrict__ Ssg) {
  const int tid = threadIdx.x;
  const int lane = tid & 63, wid = tid >> 6;
  const int l4 = lane & 15, quad = lane >> 4;
  const int wt = wid >> 1, wu = wid & 1;
  const int b = blockIdx.y, t0 = blockIdx.x * 64;

  __shared__ float sState[124];
  __shared__ float sPc[64];
  __shared__ float sBm[128];
  __shared__ float sVa[128];
  __shared__ float sSg[64];
  __shared__ float blkP0[128], blkP1[128];
  __shared__ float blkSsg;
  __shared__ __align__(16) unsigned short sS[64 * 144];  // pm tile bf16, row stride 144

  // ---- init small LDS (phase 1 does not touch LDS; barrier deferred to pre-phase-2)
  for (int i = tid; i < 124; i += 256) {
    int t = t0 - 30 + i;
    sState[i] = (t >= 0 && t < Tv) ? state[b * Tv + t] : 0.0f;
  }
  if (tid < 64) sPc[tid] = prev_cum[b * Tv + t0 + tid];
  for (int i = tid; i < 128; i += 256) {
    sBm[i] = bm[i]; sVa[i] = va[i]; blkP0[i] = 0.0f; blkP1[i] = 0.0f;
  }
  if (tid == 0) blkSsg = 0.0f;

  f32x4 acc[2][4];
  #pragma unroll
  for (int ti = 0; ti < 2; ++ti)
    #pragma unroll
    for (int uj = 0; uj < 4; ++uj) acc[ti][uj] = (f32x4){0.f, 0.f, 0.f, 0.f};

  const float* aBase = memory + ((size_t)b * Tv + t0 + wt * 32 + l4) * Mv + quad * 8;
  const unsigned short* bBase = WmF + (size_t)(wu * 4) * 512 + lane * 8;

  // ---- 4-deep A pipeline (rotating register slots, fully static after unroll)
  float4 A0[4], A1[4], A2[4], A3[4];
  #pragma unroll
  for (int s = 0; s < 4; ++s) {
    const float* p = aBase + s * 32;
    A0[s] = *(const float4*)(p);
    A1[s] = *(const float4*)(p + 4);
    A2[s] = *(const float4*)(p + (size_t)16 * Mv);
    A3[s] = *(const float4*)(p + (size_t)16 * Mv + 4);
  }
  uint4 bC0 = *(const uint4*)(bBase);
  uint4 bC1 = *(const uint4*)(bBase + 512);
  uint4 bC2 = *(const uint4*)(bBase + 1024);
  uint4 bC3 = *(const uint4*)(bBase + 1536);

  #pragma unroll
  for (int kc = 0; kc < 16; ++kc) {
    const int s = kc & 3;
    // B prefetch for kc+1 (L2-resident)
    uint4 bN0, bN1, bN2, bN3;
    if (kc < 15) {
      const unsigned short* pb = bBase + (size_t)(kc + 1) * 4096;
      bN0 = *(const uint4*)(pb);
      bN1 = *(const uint4*)(pb + 512);
      bN2 = *(const uint4*)(pb + 1024);
      bN3 = *(const uint4*)(pb + 1536);
    }
    // consume slot s
    float4 a0 = A0[s], a1 = A1[s], a2 = A2[s], a3 = A3[s];
    // refill slot s with chunk kc+4 (issued ~3 chunks of compute ahead of use)
    if (kc + 4 < 16) {
      const float* p = aBase + (kc + 4) * 32;
      A0[s] = *(const float4*)(p);
      A1[s] = *(const float4*)(p + 4);
      A2[s] = *(const float4*)(p + (size_t)16 * Mv);
      A3[s] = *(const float4*)(p + (size_t)16 * Mv + 4);
    }
    bf16x8 af0, af1;
    af0[0] = (__bf16)a0.x; af0[1] = (__bf16)a0.y; af0[2] = (__bf16)a0.z; af0[3] = (__bf16)a0.w;
    af0[4] = (__bf16)a1.x; af0[5] = (__bf16)a1.y; af0[6] = (__bf16)a1.z; af0[7] = (__bf16)a1.w;
    af1[0] = (__bf16)a2.x; af1[1] = (__bf16)a2.y; af1[2] = (__bf16)a2.z; af1[3] = (__bf16)a2.w;
    af1[4] = (__bf16)a3.x; af1[5] = (__bf16)a3.y; af1[6] = (__bf16)a3.z; af1[7] = (__bf16)a3.w;
    U4BF u0, u1, u2, u3;
    u0.u = bC0; u1.u = bC1; u2.u = bC2; u3.u = bC3;
    acc[0][0] = MFMA(af0, u0.b, acc[0][0]);
    acc[1][0] = MFMA(af1, u0.b, acc[1][0]);
    acc[0][1] = MFMA(af0, u1.b, acc[0][1]);
    acc[1][1] = MFMA(af1, u1.b, acc[1][1]);
    acc[0][2] = MFMA(af0, u2.b, acc[0][2]);
    acc[1][2] = MFMA(af1, u2.b, acc[1][2]);
    acc[0][3] = MFMA(af0, u3.b, acc[0][3]);
    acc[1][3] = MFMA(af1, u3.b, acc[1][3]);
    if (kc < 15) { bC0 = bN0; bC1 = bN1; bC2 = bN2; bC3 = bN3; }
  }

  // ---- write pm (bf16) to LDS; C layout: col=lane&15, row=quad*4+reg
  #pragma unroll
  for (int ti = 0; ti < 2; ++ti) {
    const int rowb = wt * 32 + ti * 16 + quad * 4;
    #pragma unroll
    for (int uj = 0; uj < 4; ++uj) {
      const int col = wu * 64 + uj * 16 + l4;
      #pragma unroll
      for (int r = 0; r < 4; ++r) sS[(rowb + r) * 144 + col] = f2bf(acc[ti][uj][r]);
    }
  }
  __syncthreads();

  // ---- phase 2: e2 = pm@We + S2@W3 + qe[b]
  const int w = wid;
  f32x4 e[8];
  #pragma unroll
  for (int nj = 0; nj < 8; ++nj) {
    float qv = qe[b * Uv + nj * 16 + l4];
    e[nj] = (f32x4){qv, qv, qv, qv};
  }
  bf16x8 a2f;
  #pragma unroll
  for (int j = 0; j < 8; ++j) {
    int k = quad * 8 + j;
    float v = (k < 31) ? sState[(w * 16 + l4) + 2 * k] : 0.0f;
    a2f[j] = (__bf16)v;
  }
  #pragma unroll
  for (int nj = 0; nj < 8; ++nj) {
    U4BF bb; bb.u = *(const uint4*)(W3F + (size_t)nj * 512 + lane * 8);
    e[nj] = MFMA(a2f, bb.b, e[nj]);
  }
  #pragma unroll
  for (int ks = 0; ks < 4; ++ks) {
    U4BF au;
    au.u = *(const uint4*)&sS[(w * 16 + l4) * 144 + ks * 32 + quad * 8];
    #pragma unroll
    for (int nj = 0; nj < 8; ++nj) {
      U4BF bb; bb.u = *(const uint4*)(WeF + (size_t)(ks * 8 + nj) * 512 + lane * 8);
      e[nj] = MFMA(au.b, bb.b, e[nj]);
    }
  }
  float p[4] = {0.f, 0.f, 0.f, 0.f};
  #pragma unroll
  for (int nj = 0; nj < 8; ++nj) {
    float vav = sVa[nj * 16 + l4];
    #pragma unroll
    for (int r = 0; r < 4; ++r) p[r] = fmaf(vav, tanh_fast(e[nj][r]), p[r]);
  }
  #pragma unroll
  for (int off = 1; off <= 8; off <<= 1) {
    #pragma unroll
    for (int r = 0; r < 4; ++r) p[r] += __shfl_xor(p[r], off, 64);
  }
  float sgv4[4], sgsum = 0.f;
  #pragma unroll
  for (int r = 0; r < 4; ++r) {
    sgv4[r] = sigmoid_fast(p[r]);
    sgsum += sgv4[r];
  }
  if (l4 == 0) {
    #pragma unroll
    for (int r = 0; r < 4; ++r) sSg[w * 16 + quad * 4 + r] = sgv4[r];
    atomicAdd(&blkSsg, sgsum);
  }
  __syncthreads();

  // ---- phase 3: P0/P1 accumulation from pm accumulators
  float sgl[8], pcl[8];
  #pragma unroll
  for (int ti = 0; ti < 2; ++ti)
    #pragma unroll
    for (int r = 0; r < 4; ++r) {
      int row = wt * 32 + ti * 16 + quad * 4 + r;
      sgl[ti * 4 + r] = sSg[row];
      pcl[ti * 4 + r] = sPc[row];
    }
  #pragma unroll
  for (int uj = 0; uj < 4; ++uj) {
    const int col = wu * 64 + uj * 16 + l4;
    const float bmv = sBm[col];
    float c0 = 0.f, c1 = 0.f;
    #pragma unroll
    for (int ti = 0; ti < 2; ++ti)
      #pragma unroll
      for (int r = 0; r < 4; ++r) {
        float pmv = acc[ti][uj][r] + bmv;
        c0 = fmaf(pcl[ti * 4 + r], pmv, c0);
        c1 = fmaf(sgl[ti * 4 + r], pmv, c1);
      }
    c0 += __shfl_xor(c0, 16, 64); c0 += __shfl_xor(c0, 32, 64);
    c1 += __shfl_xor(c1, 16, 64); c1 += __shfl_xor(c1, 32, 64);
    if (quad == 0) {
      atomicAdd(&blkP0[col], c0);
      atomicAdd(&blkP1[col], c1);
    }
  }
  __syncthreads();
  if (tid < 128) {
    unsafeAtomicAdd(&P0[b * Uv + tid], blkP0[tid]);
    unsafeAtomicAdd(&P1[b * Uv + tid], blkP1[tid]);
  }
  if (tid == 0) unsafeAtomicAdd(&Ssg[b], blkSsg);
}

// ---------------- finish: context = P0 + P1 / Ssg ----------------
__global__ __launch_bounds__(128) void finish_kernel(const float* __restrict__ P0,
                                                     const float* __restrict__ P1,
                                                     const float* __restrict__ Ssg,
                                                     float* __restrict__ out) {
  const int b = blockIdx.x, u = threadIdx.x;
  out[b * Uv + u] = P0[b * Uv + u] + P1[b * Uv + u] / Ssg[b];
}

extern "C" void kernel_launch(void* const* d_in, const int* in_sizes, int n_in,
                              void* d_out, int out_size, void* d_ws, size_t ws_size,
                              hipStream_t stream) {
  (void)in_sizes; (void)n_in; (void)out_size; (void)ws_size;
  const float* query    = (const float*)d_in[0];
  const float* state    = (const float*)d_in[1];
  const float* prev_cum = (const float*)d_in[2];
  const float* memory   = (const float*)d_in[3];
  const float* Wq       = (const float*)d_in[4];
  const float* bq       = (const float*)d_in[5];
  const float* Wm       = (const float*)d_in[6];
  const float* bm       = (const float*)d_in[7];
  const float* Wl       = (const float*)d_in[8];
  const float* bl       = (const float*)d_in[9];
  const float* We       = (const float*)d_in[10];
  const float* be       = (const float*)d_in[11];
  const float* va       = (const float*)d_in[12];
  const float* conv_w   = (const float*)d_in[13];
  const float* conv_b   = (const float*)d_in[14];

  float* ws = (float*)d_ws;
  float* P0    = ws;                 // 8192
  float* P1    = ws + 8192;          // 8192
  float* Ssg   = ws + 16384;         // 64
  float* pq    = ws + 16448;         // 8192
  float* W2    = ws + 24640;         // 3968
  float* bias2 = ws + 28608;         // 128
  float* qe    = ws + 28736;         // 8192
  float* w3tmp = ws + 36928;         // 4096 (32x128, row 31 zeroed)
  unsigned short* WmF = (unsigned short*)(ws + 41024);  // 65536 bf16
  unsigned short* WeF = (unsigned short*)(ws + 73792);  // 16384 bf16
  unsigned short* W3F = (unsigned short*)(ws + 81984);  // 4096 bf16

  hipMemsetAsync(d_ws, 0, 24640 * sizeof(float), stream);

  k1_kernel<<<513, 128, 0, stream>>>(query, Wq, bq, Wl, bl, conv_w, conv_b, pq, W2, bias2);
  k2_kernel<<<48, 256, 0, stream>>>(pq, bias2, bm, be, We, W2, qe, w3tmp);
  k3_kernel<<<42, 256, 0, stream>>>(Wm, We, w3tmp, WmF, WeF, W3F);
  main_kernel<<<dim3(Tv / 64, Bv), 256, 0, stream>>>(
      memory, WmF, WeF, W3F, qe, state, prev_cum, bm, va, P0, P1, Ssg);
  finish_kernel<<<Bv, 128, 0, stream>>>(P0, P1, Ssg, (float*)d_out);
}